// Round 1
// baseline (332.774 us; speedup 1.0000x reference)
//
#include <hip/hip_runtime.h>

#define BB 4
#define LL 1024
#define EE 1024
#define HH 16
#define HD 64
#define NBUCKET 33
#define SCALE 0.125f
#define SC2 (0.125f * 1.44269504088896f)

typedef unsigned short u16;
using f32x4 = __attribute__((ext_vector_type(4))) float;
using s16x8 = __attribute__((ext_vector_type(8))) short;

__device__ __forceinline__ u16 f2bf(float f) {
  union { float f; unsigned u; } x; x.f = f;
  unsigned r = (x.u + 0x7fffu + ((x.u >> 16) & 1u)) >> 16;
  return (u16)r;
}

__device__ __forceinline__ void gld_lds16(const void* g, void* s) {
  __builtin_amdgcn_global_load_lds((const __attribute__((address_space(1))) void*)g,
                                   (__attribute__((address_space(3))) void*)s, 16, 0, 0);
}

__device__ __forceinline__ float qsum16(float s) {
  s += __shfl_xor(s, 1); s += __shfl_xor(s, 2);
  s += __shfl_xor(s, 4); s += __shfl_xor(s, 8);
  return s;
}

// ---------------- fp32 -> bf16 converts (merged launches) ----------------
__global__ __launch_bounds__(256) void cvt3_bf16(const float* __restrict__ a,
                                                 const float* __restrict__ b,
                                                 const float* __restrict__ c,
                                                 u16* __restrict__ oa, u16* __restrict__ ob,
                                                 u16* __restrict__ oc, int n4) {
  const int z = blockIdx.y;
  const float* in = z == 0 ? a : (z == 1 ? b : c);
  u16* out = z == 0 ? oa : (z == 1 ? ob : oc);
  int i = blockIdx.x * 256 + threadIdx.x;
  if (i < n4) {
    float4 f = ((const float4*)in)[i];
    ushort4 o;
    o.x = f2bf(f.x); o.y = f2bf(f.y); o.z = f2bf(f.z); o.w = f2bf(f.w);
    ((ushort4*)out)[i] = o;
  }
}

// z=0..3: 4 weight matrices; z=4: rel_k (33x64 f32) -> padded (48x64 bf16)
__global__ __launch_bounds__(256) void cvt4r_bf16(const float* __restrict__ a,
                                                  const float* __restrict__ b,
                                                  const float* __restrict__ c,
                                                  const float* __restrict__ d,
                                                  const float* __restrict__ rk,
                                                  u16* __restrict__ oa, u16* __restrict__ ob,
                                                  u16* __restrict__ oc, u16* __restrict__ od,
                                                  u16* __restrict__ ork, int n4) {
  const int z = blockIdx.z;
  int i = blockIdx.x * 256 + threadIdx.x;
  if (z == 4) {
    if (i < 48 * 64) ork[i] = (i < 33 * 64) ? f2bf(rk[i]) : (u16)0;
    return;
  }
  const float* in = z == 0 ? a : (z == 1 ? b : (z == 2 ? c : d));
  u16* out = z == 0 ? oa : (z == 1 ? ob : (z == 2 ? oc : od));
  if (i < n4) {
    float4 f = ((const float4*)in)[i];
    ushort4 o;
    o.x = f2bf(f.x); o.y = f2bf(f.y); o.z = f2bf(f.z); o.w = f2bf(f.w);
    ((ushort4*)out)[i] = o;
  }
}

// ---------------- 128x128x64-tile bf16 GEMM, C = A * B^T + bias ----------------
// MODE 0: store bf16 head-layout (B,H,L,HD).
// MODE 1: store fp32 row-major [M][N].
// MODE 2: store bf16 transposed head-layout (B,H,HD,L) — packed ushort4 across r.
template <int MODE>
__device__ __forceinline__ void gemm128_bt(const u16* __restrict__ A,
                                           const u16* __restrict__ Bw,
                                           const float* __restrict__ bias,
                                           u16* __restrict__ obf,
                                           float* __restrict__ ofp,
                                           int M, int N, int K, int m0, int n0) {
  __shared__ u16 a_sm[128 * 64];
  __shared__ u16 b_sm[128 * 64];
  const int tid = threadIdx.x;
  const int wave = tid >> 6, lane = tid & 63;
  const int row16 = lane & 15, quad = lane >> 4;
  const int wr = (wave >> 1) * 64, wc = (wave & 1) * 64;
  const int srow = lane >> 3, scol = (lane & 7) * 8;

  f32x4 acc[4][4] = {};

  for (int k0 = 0; k0 < K; k0 += 64) {
#pragma unroll
    for (int t = 0; t < 4; ++t) {
      const int chunk = wave * 4 + t;
      const int r = chunk * 8 + srow;
      gld_lds16(A + (size_t)(m0 + r) * K + k0 + scol, a_sm + chunk * 512);
      gld_lds16(Bw + (size_t)(n0 + r) * K + k0 + scol, b_sm + chunk * 512);
    }
    __syncthreads();
#pragma unroll
    for (int ks = 0; ks < 2; ++ks) {
      s16x8 af[4], bf[4];
#pragma unroll
      for (int mi = 0; mi < 4; ++mi)
        af[mi] = *(const s16x8*)&a_sm[(wr + mi * 16 + row16) * 64 + ks * 32 + quad * 8];
#pragma unroll
      for (int ni = 0; ni < 4; ++ni)
        bf[ni] = *(const s16x8*)&b_sm[(wc + ni * 16 + row16) * 64 + ks * 32 + quad * 8];
#pragma unroll
      for (int mi = 0; mi < 4; ++mi)
#pragma unroll
        for (int ni = 0; ni < 4; ++ni)
          acc[mi][ni] = __builtin_amdgcn_mfma_f32_16x16x32_bf16(af[mi], bf[ni], acc[mi][ni], 0, 0, 0);
    }
    __syncthreads();
  }

#pragma unroll
  for (int mi = 0; mi < 4; ++mi)
#pragma unroll
    for (int ni = 0; ni < 4; ++ni) {
      const int n = n0 + wc + ni * 16 + row16;
      const float bn = bias[n];
      if (MODE == 2) {
        // rows r=0..3 are consecutive l -> one packed ushort4 store
        const int mr0 = m0 + wr + mi * 16 + quad * 4;
        const int b = mr0 >> 10, l = mr0 & 1023;
        const int h = n >> 6, hd = n & 63;
        ushort4 o;
        o.x = f2bf(acc[mi][ni][0] + bn);
        o.y = f2bf(acc[mi][ni][1] + bn);
        o.z = f2bf(acc[mi][ni][2] + bn);
        o.w = f2bf(acc[mi][ni][3] + bn);
        *(ushort4*)&obf[((size_t)((b * HH + h) * HD + hd)) * LL + l] = o;
      } else {
#pragma unroll
        for (int r = 0; r < 4; ++r) {
          const int m = m0 + wr + mi * 16 + quad * 4 + r;
          const float v = acc[mi][ni][r] + bn;
          if (MODE == 0) {
            const int b = m >> 10, l = m & 1023, h = n >> 6, hd = n & 63;
            obf[((size_t)((b * HH + h) * LL + l)) * HD + hd] = f2bf(v);
          } else {
            ofp[(size_t)m * N + n] = v;
          }
        }
      }
    }
}

__global__ __launch_bounds__(256) void proj_gemm(
    const u16* __restrict__ xq, const u16* __restrict__ xk, const u16* __restrict__ xv,
    const u16* __restrict__ wqb, const u16* __restrict__ wkb, const u16* __restrict__ wvb,
    const float* __restrict__ bq, const float* __restrict__ bk, const float* __restrict__ bv,
    u16* __restrict__ oq, u16* __restrict__ ok, u16* __restrict__ ovt) {
  if (blockIdx.z == 0)
    gemm128_bt<0>(xq, wqb, bq, oq, nullptr, BB * LL, EE, EE, blockIdx.y * 128, blockIdx.x * 128);
  else if (blockIdx.z == 1)
    gemm128_bt<0>(xk, wkb, bk, ok, nullptr, BB * LL, EE, EE, blockIdx.y * 128, blockIdx.x * 128);
  else  // V: store directly transposed (B,H,HD,L) — transpose_v kernel eliminated
    gemm128_bt<2>(xv, wvb, bv, ovt, nullptr, BB * LL, EE, EE, blockIdx.y * 128, blockIdx.x * 128);
}

__global__ __launch_bounds__(256) void out_gemm(const u16* __restrict__ Y,
                                                const u16* __restrict__ wob,
                                                const float* __restrict__ bo,
                                                float* __restrict__ out) {
  gemm128_bt<1>(Y, wob, bo, nullptr, out, BB * LL, EE, EE, blockIdx.y * 128, blockIdx.x * 128);
}

// ---------------- fused attention (round-6-proven, verbatim) ----------------
// grid 1024 (1D, XCD-swizzled: bh = blk & 63), block 256 (4 waves; wave w owns
// q-rows [i0+16w, i0+16w+16)). K/V fragments direct from global; no main-loop
// barriers. Far-tile shfl-sourced bias + near-tile per-element path.
// NOTE: VGPR=120 sits just under the 128 occupancy cliff (m69) — register-
// hungry pipelining here is net-negative (round-7 evidence: 152 VGPR halved
// occupancy, 142->155 us).
__global__ __launch_bounds__(256) void attn_fused(
    const u16* __restrict__ Q, const u16* __restrict__ Kb, const u16* __restrict__ Vt,
    const u16* __restrict__ RKp, const float* __restrict__ RV, u16* __restrict__ Y) {
  __shared__ __align__(16) float qr_sm[4][16 * 36];
  __shared__ __align__(16) float s_sm[4][16 * 36];
  __shared__ __align__(16) unsigned char pool[9216];  // p_w slices in loop; rv_sm in epilogue

  const int tid = threadIdx.x;
  const int wave = tid >> 6, lane = tid & 63;
  const int row16 = lane & 15, quad = lane >> 4;
  const int bh = blockIdx.x & 63;          // XCD swizzle: xcd = blk % 8 = bh % 8
  const int i0 = (blockIdx.x >> 6) * 64;
  const int wq0 = i0 + wave * 16;
  const u16* qp = Q + (size_t)bh * LL * HD;
  const u16* kp = Kb + (size_t)bh * LL * HD;
  const u16* vp = Vt + (size_t)bh * HD * LL;

  u16* p_w = (u16*)pool + wave * (16 * 72);
  float* qr_w = &qr_sm[wave][0];
  float* s_w = &s_sm[wave][0];

  for (int t = lane; t < 16 * 36; t += 64) s_w[t] = 0.f;

  // Q fragments (A-operand: m=lane&15, k=quad*8+j)
  s16x8 qf[2];
#pragma unroll
  for (int ks = 0; ks < 2; ++ks)
    qf[ks] = *(const s16x8*)(qp + (size_t)(wq0 + row16) * HD + ks * 32 + quad * 8);

  // qr[i][bucket] = q[i] . rel_k[bucket] (unscaled), buckets padded to 48.
  // Keep nt=0 and nt=2 accumulators for the register far-bias (buckets 0, 32).
  f32x4 a0, a2;
#pragma unroll
  for (int nt = 0; nt < 3; ++nt) {
    f32x4 a = {};
#pragma unroll
    for (int ks = 0; ks < 2; ++ks) {
      s16x8 bfr = *(const s16x8*)(RKp + (size_t)(nt * 16 + row16) * HD + ks * 32 + quad * 8);
      a = __builtin_amdgcn_mfma_f32_16x16x32_bf16(qf[ks], bfr, a, 0, 0, 0);
    }
    if (nt == 0) a0 = a;
    if (nt == 2) a2 = a;
    const int idx = nt * 16 + row16;
    if (idx < NBUCKET)
#pragma unroll
      for (int r = 0; r < 4; ++r) qr_w[(quad * 4 + r) * 36 + idx] = a[r];
  }
  // bucket 0 / 32 bias per row i=quad*4+r lives in lane (quad,row16=0)'s acc
  float blo[4], bhi[4];
#pragma unroll
  for (int r = 0; r < 4; ++r) {
    blo[r] = __shfl(a0[r], lane & 48);
    bhi[r] = __shfl(a2[r], lane & 48);
  }

  f32x4 oacc[4] = {};
  float rsum[4] = {0.f, 0.f, 0.f, 0.f};
  float plos[4] = {0.f, 0.f, 0.f, 0.f};
  float phis[4] = {0.f, 0.f, 0.f, 0.f};
  int dbase[4];
#pragma unroll
  for (int nt = 0; nt < 4; ++nt) dbase[nt] = nt * 16 + row16 - quad * 4 - wq0;

  for (int jt = 0; jt < 16; ++jt) {
    const int j0 = jt * 64;

    // K fragments (B-operand: n=key row, k=HD slice), direct from global
    s16x8 kfr[4][2];
#pragma unroll
    for (int nt2 = 0; nt2 < 4; ++nt2)
#pragma unroll
      for (int ks = 0; ks < 2; ++ks)
        kfr[nt2][ks] = *(const s16x8*)(kp + (size_t)(j0 + nt2 * 16 + row16) * HD + ks * 32 + quad * 8);

    // V fragments (B-operand: n=d, k=key) issued BEFORE the QK MFMAs so their
    // latency hides behind QK + softmax (consumed only at the PV MFMAs)
    s16x8 vf[4][2];
#pragma unroll
    for (int dt = 0; dt < 4; ++dt)
#pragma unroll
      for (int ks = 0; ks < 2; ++ks)
        vf[dt][ks] = *(const s16x8*)(vp + (size_t)(dt * 16 + row16) * LL + j0 + ks * 32 + quad * 8);

    // S = Q K^T (16 q-rows x 64 keys)
    f32x4 sacc[4] = {};
#pragma unroll
    for (int ks = 0; ks < 2; ++ks)
#pragma unroll
      for (int nt2 = 0; nt2 < 4; ++nt2)
        sacc[nt2] = __builtin_amdgcn_mfma_f32_16x16x32_bf16(qf[ks], kfr[nt2][ks], sacc[nt2], 0, 0, 0);

    // P = exp2((S + qr[bucket]) * SC2)
    float p[4][4];
    const bool far_lo = (wq0 >= j0 + 79);   // all dr <= -16  -> bucket 0
    const bool far_hi = (j0 >= wq0 + 31);   // all dr >= +16  -> bucket 32
    if (far_lo || far_hi) {
#pragma unroll
      for (int r = 0; r < 4; ++r) {
        const float bias = far_lo ? blo[r] : bhi[r];
        float acc = 0.f;
#pragma unroll
        for (int nt2 = 0; nt2 < 4; ++nt2) {
          const float pv = exp2f((sacc[nt2][r] + bias) * SC2);
          p[nt2][r] = pv;
          acc += pv;
        }
        rsum[r] += acc;
        if (far_lo) plos[r] += acc; else phis[r] += acc;
      }
    } else {
      // near-diagonal: per-element path (round-5/6-proven verbatim)
#pragma unroll
      for (int nt2 = 0; nt2 < 4; ++nt2)
#pragma unroll
        for (int r = 0; r < 4; ++r) {
          const int dr = dbase[nt2] + j0 - r;
          int bk = dr < -16 ? -16 : (dr > 16 ? 16 : dr);
          bk += 16;
          const float bias = qr_w[(quad * 4 + r) * 36 + bk];
          const float pv = exp2f((sacc[nt2][r] + bias) * SC2);
          p[nt2][r] = pv;
          rsum[r] += pv;
          if (dr <= -16) plos[r] += pv;
          else if (dr >= 16) phis[r] += pv;
          else atomicAdd(&s_w[(quad * 4 + r) * 36 + bk], pv);
        }
    }

    // P: C-layout -> A-layout via per-wave LDS slice (in-wave ordering suffices)
#pragma unroll
    for (int nt2 = 0; nt2 < 4; ++nt2)
#pragma unroll
      for (int r = 0; r < 4; ++r)
        p_w[(quad * 4 + r) * 72 + nt2 * 16 + row16] = f2bf(p[nt2][r]);

#pragma unroll
    for (int ks = 0; ks < 2; ++ks) {
      const s16x8 pf = *(const s16x8*)&p_w[row16 * 72 + ks * 32 + quad * 8];
#pragma unroll
      for (int dt = 0; dt < 4; ++dt)
        oacc[dt] = __builtin_amdgcn_mfma_f32_16x16x32_bf16(pf, vf[dt][ks], oacc[dt], 0, 0, 0);
    }
  }

  // post-loop reductions (once, not per tile)
  float lacc[4], slo[4], shi[4];
#pragma unroll
  for (int r = 0; r < 4; ++r) {
    lacc[r] = qsum16(rsum[r]);
    slo[r] = qsum16(plos[r]);
    shi[r] = qsum16(phis[r]);
  }

  // epilogue: rel_v into pool (after barrier so all waves' p_w reads are done)
  __syncthreads();
  float* rv_sm = (float*)pool;
  for (int t = tid; t < NBUCKET * HD; t += 256) rv_sm[t] = RV[t];
  __syncthreads();

  const int b = bh >> 4, h = bh & 15;
#pragma unroll
  for (int r = 0; r < 4; ++r) {
    const int i_loc = quad * 4 + r;
    float rel[4] = {0.f, 0.f, 0.f, 0.f};
    for (int bk = 0; bk < NBUCKET; ++bk) {
      float sv = s_w[i_loc * 36 + bk];
      if (bk == 0) sv += slo[r];
      if (bk == 32) sv += shi[r];
#pragma unroll
      for (int dt = 0; dt < 4; ++dt) rel[dt] += sv * rv_sm[bk * HD + dt * 16 + row16];
    }
    const float inv = 1.0f / lacc[r];
#pragma unroll
    for (int dt = 0; dt < 4; ++dt) {
      const float y = (oacc[dt][r] + rel[dt]) * inv;
      Y[((size_t)(b * LL + wq0 + i_loc)) * EE + h * HD + dt * 16 + row16] = f2bf(y);
    }
  }
}

extern "C" void kernel_launch(void* const* d_in, const int* in_sizes, int n_in,
                              void* d_out, int out_size, void* d_ws, size_t ws_size,
                              hipStream_t stream) {
  const float* query = (const float*)d_in[0];
  const float* key_  = (const float*)d_in[1];
  const float* value = (const float*)d_in[2];
  const float* wq = (const float*)d_in[3];
  const float* bq = (const float*)d_in[4];
  const float* wk = (const float*)d_in[5];
  const float* bk = (const float*)d_in[6];
  const float* wv = (const float*)d_in[7];
  const float* bv = (const float*)d_in[8];
  const float* wo = (const float*)d_in[9];
  const float* bo = (const float*)d_in[10];
  const float* rel_k = (const float*)d_in[11];
  const float* rel_v = (const float*)d_in[12];

  char* base = (char*)d_ws;
  size_t off = 0;
  auto alloc = [&](size_t bytes) -> void* {
    void* p = base + off;
    off += (bytes + 255) & ~(size_t)255;
    return p;
  };
  const size_t XE = (size_t)BB * LL * EE;
  u16* xq    = (u16*)alloc(XE * 2);
  u16* xk    = (u16*)alloc(XE * 2);
  u16* xv    = (u16*)alloc(XE * 2);
  u16* wqb   = (u16*)alloc((size_t)EE * EE * 2);
  u16* wkb   = (u16*)alloc((size_t)EE * EE * 2);
  u16* wvb   = (u16*)alloc((size_t)EE * EE * 2);
  u16* wob   = (u16*)alloc((size_t)EE * EE * 2);
  u16* q_ws  = (u16*)alloc(XE * 2);
  u16* k_ws  = (u16*)alloc(XE * 2);
  u16* vt_ws = (u16*)alloc(XE * 2);   // V stored transposed by proj_gemm
  u16* relkp = (u16*)alloc(48 * 64 * 2);
  u16* y_ws = xq;   // xq dead after proj_gemm (stream-ordered)

  const int nx4 = (int)(XE / 4);
  const int nw4 = EE * EE / 4;
  cvt3_bf16<<<dim3(nx4 / 256, 3), 256, 0, stream>>>(query, key_, value, xq, xk, xv, nx4);
  cvt4r_bf16<<<dim3(nw4 / 256, 1, 5), 256, 0, stream>>>(wq, wk, wv, wo, rel_k,
                                                        wqb, wkb, wvb, wob, relkp, nw4);

  proj_gemm<<<dim3(EE / 128, BB * LL / 128, 3), 256, 0, stream>>>(
      xq, xk, xv, wqb, wkb, wvb, bq, bk, bv, q_ws, k_ws, vt_ws);

  attn_fused<<<1024, 256, 0, stream>>>(q_ws, k_ws, vt_ws, relkp, rel_v, y_ws);

  out_gemm<<<dim3(EE / 128, BB * LL / 128), 256, 0, stream>>>(y_ws, wob, bo, (float*)d_out);
}

// Round 2
// 279.287 us; speedup vs baseline: 1.1915x; 1.1915x over previous
//
#include <hip/hip_runtime.h>

#define BB 4
#define LL 1024
#define EE 1024
#define HH 16
#define HD 64
#define NBUCKET 33
#define SCALE 0.125f
#define SC2 (0.125f * 1.44269504088896f)

typedef unsigned short u16;
using f32x4 = __attribute__((ext_vector_type(4))) float;
using s16x8 = __attribute__((ext_vector_type(8))) short;

__device__ __forceinline__ u16 f2bf(float f) {
  union { float f; unsigned u; } x; x.f = f;
  unsigned r = (x.u + 0x7fffu + ((x.u >> 16) & 1u)) >> 16;
  return (u16)r;
}

__device__ __forceinline__ void gld_lds16(const void* g, void* s) {
  __builtin_amdgcn_global_load_lds((const __attribute__((address_space(1))) void*)g,
                                   (__attribute__((address_space(3))) void*)s, 16, 0, 0);
}

__device__ __forceinline__ float qsum16(float s) {
  s += __shfl_xor(s, 1); s += __shfl_xor(s, 2);
  s += __shfl_xor(s, 4); s += __shfl_xor(s, 8);
  return s;
}

// ---------------- fp32 -> bf16 converts (merged launches) ----------------
__global__ __launch_bounds__(256) void cvt3_bf16(const float* __restrict__ a,
                                                 const float* __restrict__ b,
                                                 const float* __restrict__ c,
                                                 u16* __restrict__ oa, u16* __restrict__ ob,
                                                 u16* __restrict__ oc, int n4) {
  const int z = blockIdx.y;
  const float* in = z == 0 ? a : (z == 1 ? b : c);
  u16* out = z == 0 ? oa : (z == 1 ? ob : oc);
  int i = blockIdx.x * 256 + threadIdx.x;
  if (i < n4) {
    float4 f = ((const float4*)in)[i];
    ushort4 o;
    o.x = f2bf(f.x); o.y = f2bf(f.y); o.z = f2bf(f.z); o.w = f2bf(f.w);
    ((ushort4*)out)[i] = o;
  }
}

// z=0..3: 4 weight matrices; z=4: rel_k (33x64 f32) -> padded (48x64 bf16)
__global__ __launch_bounds__(256) void cvt4r_bf16(const float* __restrict__ a,
                                                  const float* __restrict__ b,
                                                  const float* __restrict__ c,
                                                  const float* __restrict__ d,
                                                  const float* __restrict__ rk,
                                                  u16* __restrict__ oa, u16* __restrict__ ob,
                                                  u16* __restrict__ oc, u16* __restrict__ od,
                                                  u16* __restrict__ ork, int n4) {
  const int z = blockIdx.z;
  int i = blockIdx.x * 256 + threadIdx.x;
  if (z == 4) {
    if (i < 48 * 64) ork[i] = (i < 33 * 64) ? f2bf(rk[i]) : (u16)0;
    return;
  }
  const float* in = z == 0 ? a : (z == 1 ? b : (z == 2 ? c : d));
  u16* out = z == 0 ? oa : (z == 1 ? ob : (z == 2 ? oc : od));
  if (i < n4) {
    float4 f = ((const float4*)in)[i];
    ushort4 o;
    o.x = f2bf(f.x); o.y = f2bf(f.y); o.z = f2bf(f.z); o.w = f2bf(f.w);
    ((ushort4*)out)[i] = o;
  }
}

// ---------------- 128x128x64-tile bf16 GEMM, C = A * B^T + bias ----------------
// MODE 0: store bf16 head-layout (B,H,L,HD).
// MODE 1: store fp32 row-major [M][N].
// MODE 2: store bf16 transposed head-layout (B,H,HD,L) — packed ushort4 across r.
template <int MODE>
__device__ __forceinline__ void gemm128_bt(const u16* __restrict__ A,
                                           const u16* __restrict__ Bw,
                                           const float* __restrict__ bias,
                                           u16* __restrict__ obf,
                                           float* __restrict__ ofp,
                                           int M, int N, int K, int m0, int n0) {
  __shared__ u16 a_sm[128 * 64];
  __shared__ u16 b_sm[128 * 64];
  const int tid = threadIdx.x;
  const int wave = tid >> 6, lane = tid & 63;
  const int row16 = lane & 15, quad = lane >> 4;
  const int wr = (wave >> 1) * 64, wc = (wave & 1) * 64;
  const int srow = lane >> 3, scol = (lane & 7) * 8;

  f32x4 acc[4][4] = {};

  for (int k0 = 0; k0 < K; k0 += 64) {
#pragma unroll
    for (int t = 0; t < 4; ++t) {
      const int chunk = wave * 4 + t;
      const int r = chunk * 8 + srow;
      gld_lds16(A + (size_t)(m0 + r) * K + k0 + scol, a_sm + chunk * 512);
      gld_lds16(Bw + (size_t)(n0 + r) * K + k0 + scol, b_sm + chunk * 512);
    }
    __syncthreads();
#pragma unroll
    for (int ks = 0; ks < 2; ++ks) {
      s16x8 af[4], bf[4];
#pragma unroll
      for (int mi = 0; mi < 4; ++mi)
        af[mi] = *(const s16x8*)&a_sm[(wr + mi * 16 + row16) * 64 + ks * 32 + quad * 8];
#pragma unroll
      for (int ni = 0; ni < 4; ++ni)
        bf[ni] = *(const s16x8*)&b_sm[(wc + ni * 16 + row16) * 64 + ks * 32 + quad * 8];
#pragma unroll
      for (int mi = 0; mi < 4; ++mi)
#pragma unroll
        for (int ni = 0; ni < 4; ++ni)
          acc[mi][ni] = __builtin_amdgcn_mfma_f32_16x16x32_bf16(af[mi], bf[ni], acc[mi][ni], 0, 0, 0);
    }
    __syncthreads();
  }

#pragma unroll
  for (int mi = 0; mi < 4; ++mi)
#pragma unroll
    for (int ni = 0; ni < 4; ++ni) {
      const int n = n0 + wc + ni * 16 + row16;
      const float bn = bias[n];
      if (MODE == 2) {
        // rows r=0..3 are consecutive l -> one packed ushort4 store
        const int mr0 = m0 + wr + mi * 16 + quad * 4;
        const int b = mr0 >> 10, l = mr0 & 1023;
        const int h = n >> 6, hd = n & 63;
        ushort4 o;
        o.x = f2bf(acc[mi][ni][0] + bn);
        o.y = f2bf(acc[mi][ni][1] + bn);
        o.z = f2bf(acc[mi][ni][2] + bn);
        o.w = f2bf(acc[mi][ni][3] + bn);
        *(ushort4*)&obf[((size_t)((b * HH + h) * HD + hd)) * LL + l] = o;
      } else {
#pragma unroll
        for (int r = 0; r < 4; ++r) {
          const int m = m0 + wr + mi * 16 + quad * 4 + r;
          const float v = acc[mi][ni][r] + bn;
          if (MODE == 0) {
            const int b = m >> 10, l = m & 1023, h = n >> 6, hd = n & 63;
            obf[((size_t)((b * HH + h) * LL + l)) * HD + hd] = f2bf(v);
          } else {
            ofp[(size_t)m * N + n] = v;
          }
        }
      }
    }
}

__global__ __launch_bounds__(256) void proj_gemm(
    const u16* __restrict__ xq, const u16* __restrict__ xk, const u16* __restrict__ xv,
    const u16* __restrict__ wqb, const u16* __restrict__ wkb, const u16* __restrict__ wvb,
    const float* __restrict__ bq, const float* __restrict__ bk, const float* __restrict__ bv,
    u16* __restrict__ oq, u16* __restrict__ ok, u16* __restrict__ ovt) {
  if (blockIdx.z == 0)
    gemm128_bt<0>(xq, wqb, bq, oq, nullptr, BB * LL, EE, EE, blockIdx.y * 128, blockIdx.x * 128);
  else if (blockIdx.z == 1)
    gemm128_bt<0>(xk, wkb, bk, ok, nullptr, BB * LL, EE, EE, blockIdx.y * 128, blockIdx.x * 128);
  else  // V: store directly transposed (B,H,HD,L) — transpose_v kernel eliminated
    gemm128_bt<2>(xv, wvb, bv, ovt, nullptr, BB * LL, EE, EE, blockIdx.y * 128, blockIdx.x * 128);
}

__global__ __launch_bounds__(256) void out_gemm(const u16* __restrict__ Y,
                                                const u16* __restrict__ wob,
                                                const float* __restrict__ bo,
                                                float* __restrict__ out) {
  gemm128_bt<1>(Y, wob, bo, nullptr, out, BB * LL, EE, EE, blockIdx.y * 128, blockIdx.x * 128);
}

// ---------------- fused attention (round 1: LDS-staged K/V) ----------------
// grid 1024, block 256 (4 waves). Per j-tile: all 4 waves cooperatively stage
// K(8KB)+V(8KB) into LDS via global_load_lds with m201-style both-sides XOR
// swizzle (linear LDS dest + pre-swizzled global source + swizzled ds_read ->
// conflict-free). This removes the per-wave scattered global K/V gather
// (was 4x redundant, 16x 64B-segment L2 transactions per load, latency-bound
// at MfmaUtil 4.9% / VALUBusy 24%).
// LDS budget: kv 17408 (K 8192 | pad 1024 | V 8192; P-pack overlays [0,9216)
// after bar-B since K region is dead post-QK-frag-reads) + qr 9216 + s 9216
// = 35840 B -> 4 blocks/CU resident (grid gives exactly 4/CU, no batch tail).
__global__ __launch_bounds__(256) void attn_fused(
    const u16* __restrict__ Q, const u16* __restrict__ Kb, const u16* __restrict__ Vt,
    const u16* __restrict__ RKp, const float* __restrict__ RV, u16* __restrict__ Y) {
  __shared__ __align__(16) float qr_sm[4][16 * 36];
  __shared__ __align__(16) float s_sm[4][16 * 36];
  __shared__ __align__(16) unsigned char kv[17408];  // K|pad|V in loop; rv_sm in epilogue

  const int tid = threadIdx.x;
  const int wave = tid >> 6, lane = tid & 63;
  const int row16 = lane & 15, quad = lane >> 4;
  const int bh = blockIdx.x & 63;          // XCD swizzle: xcd = blk % 8 = bh % 8
  const int i0 = (blockIdx.x >> 6) * 64;
  const int wq0 = i0 + wave * 16;
  const u16* qp = Q + (size_t)bh * LL * HD;
  const char* kpB = (const char*)(Kb + (size_t)bh * LL * HD);
  const char* vpB = (const char*)(Vt + (size_t)bh * HD * LL);

  u16* p_w = (u16*)(kv + wave * (16 * 72 * 2));  // overlays K region + pad
  float* qr_w = &qr_sm[wave][0];
  float* s_w = &s_sm[wave][0];

  for (int t = lane; t < 16 * 36; t += 64) s_w[t] = 0.f;

  // stage source/dest offsets (both-sides swizzle: linear LDS dest, global
  // source pre-swizzled by byte ^= ((row&7)<<4) within each 128B row)
  int srcK[2], srcV[2];
#pragma unroll
  for (int t = 0; t < 2; ++t) {
    const int cK = (wave * 2 + t) * 64 + lane;        // chunk 0..511
    const int rw = cK >> 3;                           // tile row 0..63
    const int cb = ((cK * 16) & 127) ^ ((rw & 7) << 4);
    srcK[t] = rw * 128 + cb;                          // + j0*128 per tile
    srcV[t] = rw * 2048 + cb;                         // + j0*2  per tile
  }
  const int swz = (row16 & 7) << 4;                   // frag-read swizzle

  // Q fragments (A-operand: m=lane&15, k=quad*8+j)
  s16x8 qf[2];
#pragma unroll
  for (int ks = 0; ks < 2; ++ks)
    qf[ks] = *(const s16x8*)(qp + (size_t)(wq0 + row16) * HD + ks * 32 + quad * 8);

  // qr[i][bucket] = q[i] . rel_k[bucket] (unscaled), buckets padded to 48.
  // Keep nt=0 and nt=2 accumulators for the register far-bias (buckets 0, 32).
  f32x4 a0, a2;
#pragma unroll
  for (int nt = 0; nt < 3; ++nt) {
    f32x4 a = {};
#pragma unroll
    for (int ks = 0; ks < 2; ++ks) {
      s16x8 bfr = *(const s16x8*)(RKp + (size_t)(nt * 16 + row16) * HD + ks * 32 + quad * 8);
      a = __builtin_amdgcn_mfma_f32_16x16x32_bf16(qf[ks], bfr, a, 0, 0, 0);
    }
    if (nt == 0) a0 = a;
    if (nt == 2) a2 = a;
    const int idx = nt * 16 + row16;
    if (idx < NBUCKET)
#pragma unroll
      for (int r = 0; r < 4; ++r) qr_w[(quad * 4 + r) * 36 + idx] = a[r];
  }
  // bucket 0 / 32 bias per row i=quad*4+r lives in lane (quad,row16=0)'s acc
  float blo[4], bhi[4];
#pragma unroll
  for (int r = 0; r < 4; ++r) {
    blo[r] = __shfl(a0[r], lane & 48);
    bhi[r] = __shfl(a2[r], lane & 48);
  }

  f32x4 oacc[4] = {};
  float rsum[4] = {0.f, 0.f, 0.f, 0.f};
  float plos[4] = {0.f, 0.f, 0.f, 0.f};
  float phis[4] = {0.f, 0.f, 0.f, 0.f};
  int dbase[4];
#pragma unroll
  for (int nt = 0; nt < 4; ++nt) dbase[nt] = nt * 16 + row16 - quad * 4 - wq0;

  for (int jt = 0; jt < 16; ++jt) {
    const int j0 = jt * 64;

    // ---- stage K+V tile into LDS (coalesced, shared by all 4 waves) ----
#pragma unroll
    for (int t = 0; t < 2; ++t) {
      gld_lds16(kpB + (size_t)j0 * 128 + srcK[t], kv + (wave * 2 + t) * 1024);
      gld_lds16(vpB + (size_t)j0 * 2 + srcV[t], kv + 9216 + (wave * 2 + t) * 1024);
    }
    __syncthreads();  // bar A: KV ready (compiler drains vmcnt before s_barrier)

    // ---- phase 1: K fragments from LDS (swizzled) + QK MFMAs ----
    f32x4 sacc[4] = {};
#pragma unroll
    for (int ks = 0; ks < 2; ++ks)
#pragma unroll
      for (int nt2 = 0; nt2 < 4; ++nt2) {
        const int L = (nt2 * 16 + row16) * 128 + ks * 64 + quad * 16;
        const s16x8 kfr = *(const s16x8*)(kv + (L ^ swz));
        sacc[nt2] = __builtin_amdgcn_mfma_f32_16x16x32_bf16(qf[ks], kfr, sacc[nt2], 0, 0, 0);
      }
    __syncthreads();  // bar B: all K-frag reads done -> K region reusable as P

    // ---- phase 2: softmax, P-pack, V fragments + PV MFMAs ----
    float p[4][4];
    const bool far_lo = (wq0 >= j0 + 79);   // all dr <= -16  -> bucket 0
    const bool far_hi = (j0 >= wq0 + 31);   // all dr >= +16  -> bucket 32
    if (far_lo || far_hi) {
#pragma unroll
      for (int r = 0; r < 4; ++r) {
        const float bias = far_lo ? blo[r] : bhi[r];
        float acc = 0.f;
#pragma unroll
        for (int nt2 = 0; nt2 < 4; ++nt2) {
          const float pv = exp2f((sacc[nt2][r] + bias) * SC2);
          p[nt2][r] = pv;
          acc += pv;
        }
        rsum[r] += acc;
        if (far_lo) plos[r] += acc; else phis[r] += acc;
      }
    } else {
      // near-diagonal: per-element path (round-5/6-proven verbatim)
#pragma unroll
      for (int nt2 = 0; nt2 < 4; ++nt2)
#pragma unroll
        for (int r = 0; r < 4; ++r) {
          const int dr = dbase[nt2] + j0 - r;
          int bk = dr < -16 ? -16 : (dr > 16 ? 16 : dr);
          bk += 16;
          const float bias = qr_w[(quad * 4 + r) * 36 + bk];
          const float pv = exp2f((sacc[nt2][r] + bias) * SC2);
          p[nt2][r] = pv;
          rsum[r] += pv;
          if (dr <= -16) plos[r] += pv;
          else if (dr >= 16) phis[r] += pv;
          else atomicAdd(&s_w[(quad * 4 + r) * 36 + bk], pv);
        }
    }

    // P: C-layout -> A-layout via per-wave LDS slice (in-wave ordering suffices)
#pragma unroll
    for (int nt2 = 0; nt2 < 4; ++nt2)
#pragma unroll
      for (int r = 0; r < 4; ++r)
        p_w[(quad * 4 + r) * 72 + nt2 * 16 + row16] = f2bf(p[nt2][r]);

#pragma unroll
    for (int ks = 0; ks < 2; ++ks) {
      const s16x8 pf = *(const s16x8*)&p_w[row16 * 72 + ks * 32 + quad * 8];
#pragma unroll
      for (int dt = 0; dt < 4; ++dt) {
        const int L = (dt * 16 + row16) * 128 + ks * 64 + quad * 16;
        const s16x8 vfr = *(const s16x8*)(kv + 9216 + (L ^ swz));
        oacc[dt] = __builtin_amdgcn_mfma_f32_16x16x32_bf16(pf, vfr, oacc[dt], 0, 0, 0);
      }
    }
    __syncthreads();  // bar C: all V-frag/P reads done -> buffer reusable
  }

  // post-loop reductions (once, not per tile)
  float lacc[4], slo[4], shi[4];
#pragma unroll
  for (int r = 0; r < 4; ++r) {
    lacc[r] = qsum16(rsum[r]);
    slo[r] = qsum16(plos[r]);
    shi[r] = qsum16(phis[r]);
  }

  // epilogue: rel_v into kv buffer (bar C already fenced all loop reads)
  __syncthreads();
  float* rv_sm = (float*)kv;
  for (int t = tid; t < NBUCKET * HD; t += 256) rv_sm[t] = RV[t];
  __syncthreads();

  const int b = bh >> 4, h = bh & 15;
#pragma unroll
  for (int r = 0; r < 4; ++r) {
    const int i_loc = quad * 4 + r;
    float rel[4] = {0.f, 0.f, 0.f, 0.f};
    for (int bk = 0; bk < NBUCKET; ++bk) {
      float sv = s_w[i_loc * 36 + bk];
      if (bk == 0) sv += slo[r];
      if (bk == 32) sv += shi[r];
#pragma unroll
      for (int dt = 0; dt < 4; ++dt) rel[dt] += sv * rv_sm[bk * HD + dt * 16 + row16];
    }
    const float inv = 1.0f / lacc[r];
#pragma unroll
    for (int dt = 0; dt < 4; ++dt) {
      const float y = (oacc[dt][r] + rel[dt]) * inv;
      Y[((size_t)(b * LL + wq0 + i_loc)) * EE + h * HD + dt * 16 + row16] = f2bf(y);
    }
  }
}

extern "C" void kernel_launch(void* const* d_in, const int* in_sizes, int n_in,
                              void* d_out, int out_size, void* d_ws, size_t ws_size,
                              hipStream_t stream) {
  const float* query = (const float*)d_in[0];
  const float* key_  = (const float*)d_in[1];
  const float* value = (const float*)d_in[2];
  const float* wq = (const float*)d_in[3];
  const float* bq = (const float*)d_in[4];
  const float* wk = (const float*)d_in[5];
  const float* bk = (const float*)d_in[6];
  const float* wv = (const float*)d_in[7];
  const float* bv = (const float*)d_in[8];
  const float* wo = (const float*)d_in[9];
  const float* bo = (const float*)d_in[10];
  const float* rel_k = (const float*)d_in[11];
  const float* rel_v = (const float*)d_in[12];

  char* base = (char*)d_ws;
  size_t off = 0;
  auto alloc = [&](size_t bytes) -> void* {
    void* p = base + off;
    off += (bytes + 255) & ~(size_t)255;
    return p;
  };
  const size_t XE = (size_t)BB * LL * EE;
  u16* xq    = (u16*)alloc(XE * 2);
  u16* xk    = (u16*)alloc(XE * 2);
  u16* xv    = (u16*)alloc(XE * 2);
  u16* wqb   = (u16*)alloc((size_t)EE * EE * 2);
  u16* wkb   = (u16*)alloc((size_t)EE * EE * 2);
  u16* wvb   = (u16*)alloc((size_t)EE * EE * 2);
  u16* wob   = (u16*)alloc((size_t)EE * EE * 2);
  u16* q_ws  = (u16*)alloc(XE * 2);
  u16* k_ws  = (u16*)alloc(XE * 2);
  u16* vt_ws = (u16*)alloc(XE * 2);   // V stored transposed by proj_gemm
  u16* relkp = (u16*)alloc(48 * 64 * 2);
  u16* y_ws = xq;   // xq dead after proj_gemm (stream-ordered)

  const int nx4 = (int)(XE / 4);
  const int nw4 = EE * EE / 4;
  cvt3_bf16<<<dim3(nx4 / 256, 3), 256, 0, stream>>>(query, key_, value, xq, xk, xv, nx4);
  cvt4r_bf16<<<dim3(nw4 / 256, 1, 5), 256, 0, stream>>>(wq, wk, wv, wo, rel_k,
                                                        wqb, wkb, wvb, wob, relkp, nw4);

  proj_gemm<<<dim3(EE / 128, BB * LL / 128, 3), 256, 0, stream>>>(
      xq, xk, xv, wqb, wkb, wvb, bq, bk, bv, q_ws, k_ws, vt_ws);

  attn_fused<<<1024, 256, 0, stream>>>(q_ws, k_ws, vt_ws, relkp, rel_v, y_ws);

  out_gemm<<<dim3(EE / 128, BB * LL / 128), 256, 0, stream>>>(y_ws, wob, bo, (float*)d_out);
}

// Round 3
// 278.819 us; speedup vs baseline: 1.1935x; 1.0017x over previous
//
#include <hip/hip_runtime.h>

#define BB 4
#define LL 1024
#define EE 1024
#define HH 16
#define HD 64
#define NBUCKET 33
#define SCALE 0.125f
#define SC2 (0.125f * 1.44269504088896f)

typedef unsigned short u16;
using f32x4 = __attribute__((ext_vector_type(4))) float;
using s16x8 = __attribute__((ext_vector_type(8))) short;

__device__ __forceinline__ u16 f2bf(float f) {
  union { float f; unsigned u; } x; x.f = f;
  unsigned r = (x.u + 0x7fffu + ((x.u >> 16) & 1u)) >> 16;
  return (u16)r;
}

__device__ __forceinline__ void gld_lds16(const void* g, void* s) {
  __builtin_amdgcn_global_load_lds((const __attribute__((address_space(1))) void*)g,
                                   (__attribute__((address_space(3))) void*)s, 16, 0, 0);
}

__device__ __forceinline__ float qsum16(float s) {
  s += __shfl_xor(s, 1); s += __shfl_xor(s, 2);
  s += __shfl_xor(s, 4); s += __shfl_xor(s, 8);
  return s;
}

// ---------------- fp32 -> bf16 converts (single merged launch) ----------------
// flat 1D grid: [0,12288) q/k/v inputs (3 x 4096 blocks, exact), [12288,16384)
// weights (4 x 1024 blocks, exact), [16384,16396) rel_k pad-to-48x64.
__global__ __launch_bounds__(256) void cvt_all(
    const float* __restrict__ q, const float* __restrict__ k, const float* __restrict__ v,
    const float* __restrict__ wq, const float* __restrict__ wk, const float* __restrict__ wv,
    const float* __restrict__ wo, const float* __restrict__ rk,
    u16* __restrict__ oq, u16* __restrict__ ok, u16* __restrict__ ov,
    u16* __restrict__ owq, u16* __restrict__ owk, u16* __restrict__ owv,
    u16* __restrict__ owo, u16* __restrict__ ork) {
  const int bid = blockIdx.x;
  const int tid = threadIdx.x;
  if (bid < 12288) {
    const int z = bid >> 12;
    const int i = (bid & 4095) * 256 + tid;
    const float* in = z == 0 ? q : (z == 1 ? k : v);
    u16* out = z == 0 ? oq : (z == 1 ? ok : ov);
    float4 f = ((const float4*)in)[i];
    ushort4 o;
    o.x = f2bf(f.x); o.y = f2bf(f.y); o.z = f2bf(f.z); o.w = f2bf(f.w);
    ((ushort4*)out)[i] = o;
  } else if (bid < 16384) {
    const int z = (bid - 12288) >> 10;
    const int i = ((bid - 12288) & 1023) * 256 + tid;
    const float* in = z == 0 ? wq : (z == 1 ? wk : (z == 2 ? wv : wo));
    u16* out = z == 0 ? owq : (z == 1 ? owk : (z == 2 ? owv : owo));
    float4 f = ((const float4*)in)[i];
    ushort4 o;
    o.x = f2bf(f.x); o.y = f2bf(f.y); o.z = f2bf(f.z); o.w = f2bf(f.w);
    ((ushort4*)out)[i] = o;
  } else {
    const int i = (bid - 16384) * 256 + tid;  // 12*256 = 3072 = 48*64 exact
    ork[i] = (i < 33 * 64) ? f2bf(rk[i]) : (u16)0;
  }
}

// ---------------- 128x128x64-tile bf16 GEMM, C = A * B^T + bias ----------------
// MODE 0: store bf16 head-layout (B,H,L,HD).
// MODE 1: store fp32 row-major [M][N].
// MODE 2: store bf16 transposed head-layout (B,H,HD,L) — packed ushort4 across r.
template <int MODE>
__device__ __forceinline__ void gemm128_bt(const u16* __restrict__ A,
                                           const u16* __restrict__ Bw,
                                           const float* __restrict__ bias,
                                           u16* __restrict__ obf,
                                           float* __restrict__ ofp,
                                           int M, int N, int K, int m0, int n0) {
  __shared__ u16 a_sm[128 * 64];
  __shared__ u16 b_sm[128 * 64];
  const int tid = threadIdx.x;
  const int wave = tid >> 6, lane = tid & 63;
  const int row16 = lane & 15, quad = lane >> 4;
  const int wr = (wave >> 1) * 64, wc = (wave & 1) * 64;
  const int srow = lane >> 3, scol = (lane & 7) * 8;

  f32x4 acc[4][4] = {};

  for (int k0 = 0; k0 < K; k0 += 64) {
#pragma unroll
    for (int t = 0; t < 4; ++t) {
      const int chunk = wave * 4 + t;
      const int r = chunk * 8 + srow;
      gld_lds16(A + (size_t)(m0 + r) * K + k0 + scol, a_sm + chunk * 512);
      gld_lds16(Bw + (size_t)(n0 + r) * K + k0 + scol, b_sm + chunk * 512);
    }
    __syncthreads();
#pragma unroll
    for (int ks = 0; ks < 2; ++ks) {
      s16x8 af[4], bf[4];
#pragma unroll
      for (int mi = 0; mi < 4; ++mi)
        af[mi] = *(const s16x8*)&a_sm[(wr + mi * 16 + row16) * 64 + ks * 32 + quad * 8];
#pragma unroll
      for (int ni = 0; ni < 4; ++ni)
        bf[ni] = *(const s16x8*)&b_sm[(wc + ni * 16 + row16) * 64 + ks * 32 + quad * 8];
#pragma unroll
      for (int mi = 0; mi < 4; ++mi)
#pragma unroll
        for (int ni = 0; ni < 4; ++ni)
          acc[mi][ni] = __builtin_amdgcn_mfma_f32_16x16x32_bf16(af[mi], bf[ni], acc[mi][ni], 0, 0, 0);
    }
    __syncthreads();
  }

#pragma unroll
  for (int mi = 0; mi < 4; ++mi)
#pragma unroll
    for (int ni = 0; ni < 4; ++ni) {
      const int n = n0 + wc + ni * 16 + row16;
      const float bn = bias[n];
      if (MODE == 2) {
        // rows r=0..3 are consecutive l -> one packed ushort4 store
        const int mr0 = m0 + wr + mi * 16 + quad * 4;
        const int b = mr0 >> 10, l = mr0 & 1023;
        const int h = n >> 6, hd = n & 63;
        ushort4 o;
        o.x = f2bf(acc[mi][ni][0] + bn);
        o.y = f2bf(acc[mi][ni][1] + bn);
        o.z = f2bf(acc[mi][ni][2] + bn);
        o.w = f2bf(acc[mi][ni][3] + bn);
        *(ushort4*)&obf[((size_t)((b * HH + h) * HD + hd)) * LL + l] = o;
      } else {
#pragma unroll
        for (int r = 0; r < 4; ++r) {
          const int m = m0 + wr + mi * 16 + quad * 4 + r;
          const float v = acc[mi][ni][r] + bn;
          if (MODE == 0) {
            const int b = m >> 10, l = m & 1023, h = n >> 6, hd = n & 63;
            obf[((size_t)((b * HH + h) * LL + l)) * HD + hd] = f2bf(v);
          } else {
            ofp[(size_t)m * N + n] = v;
          }
        }
      }
    }
}

__global__ __launch_bounds__(256) void proj_gemm(
    const u16* __restrict__ xq, const u16* __restrict__ xk, const u16* __restrict__ xv,
    const u16* __restrict__ wqb, const u16* __restrict__ wkb, const u16* __restrict__ wvb,
    const float* __restrict__ bq, const float* __restrict__ bk, const float* __restrict__ bv,
    u16* __restrict__ oq, u16* __restrict__ ok, u16* __restrict__ ovt) {
  if (blockIdx.z == 0)
    gemm128_bt<0>(xq, wqb, bq, oq, nullptr, BB * LL, EE, EE, blockIdx.y * 128, blockIdx.x * 128);
  else if (blockIdx.z == 1)
    gemm128_bt<0>(xk, wkb, bk, ok, nullptr, BB * LL, EE, EE, blockIdx.y * 128, blockIdx.x * 128);
  else  // V: store directly transposed (B,H,HD,L) — transpose_v kernel eliminated
    gemm128_bt<2>(xv, wvb, bv, ovt, nullptr, BB * LL, EE, EE, blockIdx.y * 128, blockIdx.x * 128);
}

__global__ __launch_bounds__(256) void out_gemm(const u16* __restrict__ Y,
                                                const u16* __restrict__ wob,
                                                const float* __restrict__ bo,
                                                float* __restrict__ out) {
  gemm128_bt<1>(Y, wob, bo, nullptr, out, BB * LL, EE, EE, blockIdx.y * 128, blockIdx.x * 128);
}

// ---------------- fused attention (round 3: double-buffered K/V staging) ----------------
// grid 1024, block 256 (4 waves). Round-2 left >50% of cycles idle: each iter
// issued its stage then hit __syncthreads -> vmcnt(0) drain exposed full L2
// latency x16. Now: 2 KV buffers; stage(jt+1) issued at TOP of iter jt, drained
// only at iter END (raw s_barrier + explicit asm waitcnt; ~800cy of QK/softmax/
// PV covers the load latency). Mid-iter barrier is lgkm-only (prefetch stays in
// flight across it; no wave touches buf[nxt] before the end-of-iter drain).
// LDS: 2x17408 (K 8K | pad 1K (P-pack overlay, dead-K region) | V 8K) + qr 9216
// + s 9216 = 53248 -> 3 blocks/CU (was 4; the 4th was idle-waiting anyway).
// P-pack uses v_cvt_pk_bf16_f32 (2 ops/pair vs 8 for scalar f2bf).
__global__ __launch_bounds__(256) void attn_fused(
    const u16* __restrict__ Q, const u16* __restrict__ Kb, const u16* __restrict__ Vt,
    const u16* __restrict__ RKp, const float* __restrict__ RV, u16* __restrict__ Y) {
  __shared__ __align__(16) float qr_sm[4][16 * 36];
  __shared__ __align__(16) float s_sm[4][16 * 36];
  __shared__ __align__(16) unsigned char kv[2][17408];  // dbuf; rv_sm overlays kv[0] in epilogue

  const int tid = threadIdx.x;
  const int wave = tid >> 6, lane = tid & 63;
  const int row16 = lane & 15, quad = lane >> 4;
  const int bh = blockIdx.x & 63;          // XCD swizzle: xcd = blk % 8 = bh % 8
  const int i0 = (blockIdx.x >> 6) * 64;
  const int wq0 = i0 + wave * 16;
  const u16* qp = Q + (size_t)bh * LL * HD;
  const char* kpB = (const char*)(Kb + (size_t)bh * LL * HD);
  const char* vpB = (const char*)(Vt + (size_t)bh * HD * LL);

  float* qr_w = &qr_sm[wave][0];
  float* s_w = &s_sm[wave][0];

  // stage source/dest offsets (both-sides swizzle: linear LDS dest, global
  // source pre-swizzled by byte ^= ((row&7)<<4) within each 128B row)
  int srcK[2], srcV[2];
#pragma unroll
  for (int t = 0; t < 2; ++t) {
    const int cK = (wave * 2 + t) * 64 + lane;        // chunk 0..511
    const int rw = cK >> 3;                           // tile row 0..63
    const int cb = ((cK * 16) & 127) ^ ((rw & 7) << 4);
    srcK[t] = rw * 128 + cb;                          // + j0*128 per tile
    srcV[t] = rw * 2048 + cb;                         // + j0*2  per tile
  }
  const int swz = (row16 & 7) << 4;                   // frag-read swizzle

  // ---- prologue: issue stage of tile 0 FIRST, overlap with qr compute ----
#pragma unroll
  for (int t = 0; t < 2; ++t) {
    gld_lds16(kpB + srcK[t], kv[0] + (wave * 2 + t) * 1024);
    gld_lds16(vpB + srcV[t], kv[0] + 9216 + (wave * 2 + t) * 1024);
  }

  for (int t = lane; t < 16 * 36; t += 64) s_w[t] = 0.f;

  // Q fragments (A-operand: m=lane&15, k=quad*8+j)
  s16x8 qf[2];
#pragma unroll
  for (int ks = 0; ks < 2; ++ks)
    qf[ks] = *(const s16x8*)(qp + (size_t)(wq0 + row16) * HD + ks * 32 + quad * 8);

  // qr[i][bucket] = q[i] . rel_k[bucket] (unscaled), buckets padded to 48.
  // Keep nt=0 and nt=2 accumulators for the register far-bias (buckets 0, 32).
  f32x4 a0, a2;
#pragma unroll
  for (int nt = 0; nt < 3; ++nt) {
    f32x4 a = {};
#pragma unroll
    for (int ks = 0; ks < 2; ++ks) {
      s16x8 bfr = *(const s16x8*)(RKp + (size_t)(nt * 16 + row16) * HD + ks * 32 + quad * 8);
      a = __builtin_amdgcn_mfma_f32_16x16x32_bf16(qf[ks], bfr, a, 0, 0, 0);
    }
    if (nt == 0) a0 = a;
    if (nt == 2) a2 = a;
    const int idx = nt * 16 + row16;
    if (idx < NBUCKET)
#pragma unroll
      for (int r = 0; r < 4; ++r) qr_w[(quad * 4 + r) * 36 + idx] = a[r];
  }
  // bucket 0 / 32 bias per row i=quad*4+r lives in lane (quad,row16=0)'s acc
  float blo[4], bhi[4];
#pragma unroll
  for (int r = 0; r < 4; ++r) {
    blo[r] = __shfl(a0[r], lane & 48);
    bhi[r] = __shfl(a2[r], lane & 48);
  }

  f32x4 oacc[4] = {};
  float rsum[4] = {0.f, 0.f, 0.f, 0.f};
  float plos[4] = {0.f, 0.f, 0.f, 0.f};
  float phis[4] = {0.f, 0.f, 0.f, 0.f};
  int dbase[4];
#pragma unroll
  for (int nt = 0; nt < 4; ++nt) dbase[nt] = nt * 16 + row16 - quad * 4 - wq0;

  // prologue drain: stage(0) + qf/qr loads complete, qr/s LDS writes done
  asm volatile("s_waitcnt vmcnt(0) lgkmcnt(0)" ::: "memory");
  __builtin_amdgcn_s_barrier();
  __builtin_amdgcn_sched_barrier(0);

  for (int jt = 0; jt < 16; ++jt) {
    const int j0 = jt * 64;
    unsigned char* kcur = (unsigned char*)kv[jt & 1];
    unsigned char* knxt = (unsigned char*)kv[(jt & 1) ^ 1];
    u16* p_w = (u16*)(kcur) + wave * 1152;  // P overlays dead K region + pad of cur

    // ---- issue prefetch of tile jt+1 (drained only at end of this iter) ----
    if (jt < 15) {
      const size_t j1 = (size_t)(j0 + 64);
#pragma unroll
      for (int t = 0; t < 2; ++t) {
        gld_lds16(kpB + j1 * 128 + srcK[t], knxt + (wave * 2 + t) * 1024);
        gld_lds16(vpB + j1 * 2 + srcV[t], knxt + 9216 + (wave * 2 + t) * 1024);
      }
    }

    // ---- phase 1: K fragments from LDS (swizzled) + QK MFMAs ----
    f32x4 sacc[4] = {};
#pragma unroll
    for (int ks = 0; ks < 2; ++ks)
#pragma unroll
      for (int nt2 = 0; nt2 < 4; ++nt2) {
        const int L = (nt2 * 16 + row16) * 128 + ks * 64 + quad * 16;
        const s16x8 kfr = *(const s16x8*)(kcur + (L ^ swz));
        sacc[nt2] = __builtin_amdgcn_mfma_f32_16x16x32_bf16(qf[ks], kfr, sacc[nt2], 0, 0, 0);
      }
    // mid barrier: K region of cur now dead -> reusable as P. lgkm-only drain;
    // the prefetch loads stay in flight across this barrier (the point of dbuf).
    asm volatile("s_waitcnt lgkmcnt(0)" ::: "memory");
    __builtin_amdgcn_s_barrier();
    __builtin_amdgcn_sched_barrier(0);

    // ---- phase 2: softmax, P-pack, V fragments + PV MFMAs ----
    float p[4][4];
    const bool far_lo = (wq0 >= j0 + 79);   // all dr <= -16  -> bucket 0
    const bool far_hi = (j0 >= wq0 + 31);   // all dr >= +16  -> bucket 32
    if (far_lo || far_hi) {
#pragma unroll
      for (int r = 0; r < 4; ++r) {
        const float bias = far_lo ? blo[r] : bhi[r];
        float acc = 0.f;
#pragma unroll
        for (int nt2 = 0; nt2 < 4; ++nt2) {
          const float pv = exp2f((sacc[nt2][r] + bias) * SC2);
          p[nt2][r] = pv;
          acc += pv;
        }
        rsum[r] += acc;
        if (far_lo) plos[r] += acc; else phis[r] += acc;
      }
    } else {
      // near-diagonal: per-element path (round-5/6-proven verbatim)
#pragma unroll
      for (int nt2 = 0; nt2 < 4; ++nt2)
#pragma unroll
        for (int r = 0; r < 4; ++r) {
          const int dr = dbase[nt2] + j0 - r;
          int bk = dr < -16 ? -16 : (dr > 16 ? 16 : dr);
          bk += 16;
          const float bias = qr_w[(quad * 4 + r) * 36 + bk];
          const float pv = exp2f((sacc[nt2][r] + bias) * SC2);
          p[nt2][r] = pv;
          rsum[r] += pv;
          if (dr <= -16) plos[r] += pv;
          else if (dr >= 16) phis[r] += pv;
          else atomicAdd(&s_w[(quad * 4 + r) * 36 + bk], pv);
        }
    }

    // P: C-layout -> A-layout via per-wave LDS slice (in-wave ordering suffices).
    // v_cvt_pk_bf16_f32 packs the r-pair in one op (RNE, matches f2bf).
#pragma unroll
    for (int nt2 = 0; nt2 < 4; ++nt2) {
      const int c = nt2 * 16 + row16;
#pragma unroll
      for (int rr = 0; rr < 2; ++rr) {
        unsigned pk;
        asm("v_cvt_pk_bf16_f32 %0, %1, %2" : "=v"(pk)
            : "v"(p[nt2][rr * 2]), "v"(p[nt2][rr * 2 + 1]));
        p_w[(quad * 4 + rr * 2) * 72 + c] = (u16)pk;
        p_w[(quad * 4 + rr * 2 + 1) * 72 + c] = (u16)(pk >> 16);
      }
    }

#pragma unroll
    for (int ks = 0; ks < 2; ++ks) {
      const s16x8 pf = *(const s16x8*)&p_w[row16 * 72 + ks * 32 + quad * 8];
#pragma unroll
      for (int dt = 0; dt < 4; ++dt) {
        const int L = (dt * 16 + row16) * 128 + ks * 64 + quad * 16;
        const s16x8 vfr = *(const s16x8*)(kcur + 9216 + (L ^ swz));
        oacc[dt] = __builtin_amdgcn_mfma_f32_16x16x32_bf16(pf, vfr, oacc[dt], 0, 0, 0);
      }
    }

    // end-of-iter: prefetch (issued ~800cy ago) drained here; all LDS reads of
    // cur consumed. Next iter may then DMA into cur and read nxt.
    asm volatile("s_waitcnt vmcnt(0) lgkmcnt(0)" ::: "memory");
    __builtin_amdgcn_s_barrier();
    __builtin_amdgcn_sched_barrier(0);
  }

  // post-loop reductions (once, not per tile)
  float lacc[4], slo[4], shi[4];
#pragma unroll
  for (int r = 0; r < 4; ++r) {
    lacc[r] = qsum16(rsum[r]);
    slo[r] = qsum16(plos[r]);
    shi[r] = qsum16(phis[r]);
  }

  // epilogue: rel_v into kv[0] (final loop barrier fenced all reads)
  float* rv_sm = (float*)kv[0];
  for (int t = tid; t < NBUCKET * HD; t += 256) rv_sm[t] = RV[t];
  __syncthreads();

  const int b = bh >> 4, h = bh & 15;
#pragma unroll
  for (int r = 0; r < 4; ++r) {
    const int i_loc = quad * 4 + r;
    float rel[4] = {0.f, 0.f, 0.f, 0.f};
    for (int bk = 0; bk < NBUCKET; ++bk) {
      float sv = s_w[i_loc * 36 + bk];
      if (bk == 0) sv += slo[r];
      if (bk == 32) sv += shi[r];
#pragma unroll
      for (int dt = 0; dt < 4; ++dt) rel[dt] += sv * rv_sm[bk * HD + dt * 16 + row16];
    }
    const float inv = 1.0f / lacc[r];
#pragma unroll
    for (int dt = 0; dt < 4; ++dt) {
      const float y = (oacc[dt][r] + rel[dt]) * inv;
      Y[((size_t)(b * LL + wq0 + i_loc)) * EE + h * HD + dt * 16 + row16] = f2bf(y);
    }
  }
}

extern "C" void kernel_launch(void* const* d_in, const int* in_sizes, int n_in,
                              void* d_out, int out_size, void* d_ws, size_t ws_size,
                              hipStream_t stream) {
  const float* query = (const float*)d_in[0];
  const float* key_  = (const float*)d_in[1];
  const float* value = (const float*)d_in[2];
  const float* wq = (const float*)d_in[3];
  const float* bq = (const float*)d_in[4];
  const float* wk = (const float*)d_in[5];
  const float* bk = (const float*)d_in[6];
  const float* wv = (const float*)d_in[7];
  const float* bv = (const float*)d_in[8];
  const float* wo = (const float*)d_in[9];
  const float* bo = (const float*)d_in[10];
  const float* rel_k = (const float*)d_in[11];
  const float* rel_v = (const float*)d_in[12];

  char* base = (char*)d_ws;
  size_t off = 0;
  auto alloc = [&](size_t bytes) -> void* {
    void* p = base + off;
    off += (bytes + 255) & ~(size_t)255;
    return p;
  };
  const size_t XE = (size_t)BB * LL * EE;
  u16* xq    = (u16*)alloc(XE * 2);
  u16* xk    = (u16*)alloc(XE * 2);
  u16* xv    = (u16*)alloc(XE * 2);
  u16* wqb   = (u16*)alloc((size_t)EE * EE * 2);
  u16* wkb   = (u16*)alloc((size_t)EE * EE * 2);
  u16* wvb   = (u16*)alloc((size_t)EE * EE * 2);
  u16* wob   = (u16*)alloc((size_t)EE * EE * 2);
  u16* q_ws  = (u16*)alloc(XE * 2);
  u16* k_ws  = (u16*)alloc(XE * 2);
  u16* vt_ws = (u16*)alloc(XE * 2);   // V stored transposed by proj_gemm
  u16* relkp = (u16*)alloc(48 * 64 * 2);
  u16* y_ws = xq;   // xq dead after proj_gemm (stream-ordered)

  cvt_all<<<16396, 256, 0, stream>>>(query, key_, value, wq, wk, wv, wo, rel_k,
                                     xq, xk, xv, wqb, wkb, wvb, wob, relkp);

  proj_gemm<<<dim3(EE / 128, BB * LL / 128, 3), 256, 0, stream>>>(
      xq, xk, xv, wqb, wkb, wvb, bq, bk, bv, q_ws, k_ws, vt_ws);

  attn_fused<<<1024, 256, 0, stream>>>(q_ws, k_ws, vt_ws, relkp, rel_v, y_ws);

  out_gemm<<<dim3(EE / 128, BB * LL / 128), 256, 0, stream>>>(y_ws, wob, bo, (float*)d_out);
}

// Round 4
// 250.706 us; speedup vs baseline: 1.3273x; 1.1121x over previous
//
#include <hip/hip_runtime.h>

#define BB 4
#define LL 1024
#define EE 1024
#define HH 16
#define HD 64
#define NBUCKET 33
#define SCALE 0.125f
#define SC2 (0.125f * 1.44269504088896f)

typedef unsigned short u16;
using f32x4 = __attribute__((ext_vector_type(4))) float;
using s16x8 = __attribute__((ext_vector_type(8))) short;

__device__ __forceinline__ u16 f2bf(float f) {
  union { float f; unsigned u; } x; x.f = f;
  unsigned r = (x.u + 0x7fffu + ((x.u >> 16) & 1u)) >> 16;
  return (u16)r;
}

__device__ __forceinline__ void gld_lds16(const void* g, void* s) {
  __builtin_amdgcn_global_load_lds((const __attribute__((address_space(1))) void*)g,
                                   (__attribute__((address_space(3))) void*)s, 16, 0, 0);
}

// ---------------- fp32 -> bf16 converts (single merged launch) ----------------
__global__ __launch_bounds__(256) void cvt_all(
    const float* __restrict__ q, const float* __restrict__ k, const float* __restrict__ v,
    const float* __restrict__ wq, const float* __restrict__ wk, const float* __restrict__ wv,
    const float* __restrict__ wo, const float* __restrict__ rk,
    u16* __restrict__ oq, u16* __restrict__ ok, u16* __restrict__ ov,
    u16* __restrict__ owq, u16* __restrict__ owk, u16* __restrict__ owv,
    u16* __restrict__ owo, u16* __restrict__ ork) {
  const int bid = blockIdx.x;
  const int tid = threadIdx.x;
  if (bid < 12288) {
    const int z = bid >> 12;
    const int i = (bid & 4095) * 256 + tid;
    const float* in = z == 0 ? q : (z == 1 ? k : v);
    u16* out = z == 0 ? oq : (z == 1 ? ok : ov);
    float4 f = ((const float4*)in)[i];
    ushort4 o;
    o.x = f2bf(f.x); o.y = f2bf(f.y); o.z = f2bf(f.z); o.w = f2bf(f.w);
    ((ushort4*)out)[i] = o;
  } else if (bid < 16384) {
    const int z = (bid - 12288) >> 10;
    const int i = ((bid - 12288) & 1023) * 256 + tid;
    const float* in = z == 0 ? wq : (z == 1 ? wk : (z == 2 ? wv : wo));
    u16* out = z == 0 ? owq : (z == 1 ? owk : (z == 2 ? owv : owo));
    float4 f = ((const float4*)in)[i];
    ushort4 o;
    o.x = f2bf(f.x); o.y = f2bf(f.y); o.z = f2bf(f.z); o.w = f2bf(f.w);
    ((ushort4*)out)[i] = o;
  } else {
    const int i = (bid - 16384) * 256 + tid;  // 12*256 = 3072 = 48*64 exact
    ork[i] = (i < 33 * 64) ? f2bf(rk[i]) : (u16)0;
  }
}

// ---------------- 128x128x64-tile bf16 GEMM, C = A * B^T + bias ----------------
template <int MODE>
__device__ __forceinline__ void gemm128_bt(const u16* __restrict__ A,
                                           const u16* __restrict__ Bw,
                                           const float* __restrict__ bias,
                                           u16* __restrict__ obf,
                                           float* __restrict__ ofp,
                                           int M, int N, int K, int m0, int n0) {
  __shared__ u16 a_sm[128 * 64];
  __shared__ u16 b_sm[128 * 64];
  const int tid = threadIdx.x;
  const int wave = tid >> 6, lane = tid & 63;
  const int row16 = lane & 15, quad = lane >> 4;
  const int wr = (wave >> 1) * 64, wc = (wave & 1) * 64;
  const int srow = lane >> 3, scol = (lane & 7) * 8;

  f32x4 acc[4][4] = {};

  for (int k0 = 0; k0 < K; k0 += 64) {
#pragma unroll
    for (int t = 0; t < 4; ++t) {
      const int chunk = wave * 4 + t;
      const int r = chunk * 8 + srow;
      gld_lds16(A + (size_t)(m0 + r) * K + k0 + scol, a_sm + chunk * 512);
      gld_lds16(Bw + (size_t)(n0 + r) * K + k0 + scol, b_sm + chunk * 512);
    }
    __syncthreads();
#pragma unroll
    for (int ks = 0; ks < 2; ++ks) {
      s16x8 af[4], bf[4];
#pragma unroll
      for (int mi = 0; mi < 4; ++mi)
        af[mi] = *(const s16x8*)&a_sm[(wr + mi * 16 + row16) * 64 + ks * 32 + quad * 8];
#pragma unroll
      for (int ni = 0; ni < 4; ++ni)
        bf[ni] = *(const s16x8*)&b_sm[(wc + ni * 16 + row16) * 64 + ks * 32 + quad * 8];
#pragma unroll
      for (int mi = 0; mi < 4; ++mi)
#pragma unroll
        for (int ni = 0; ni < 4; ++ni)
          acc[mi][ni] = __builtin_amdgcn_mfma_f32_16x16x32_bf16(af[mi], bf[ni], acc[mi][ni], 0, 0, 0);
    }
    __syncthreads();
  }

#pragma unroll
  for (int mi = 0; mi < 4; ++mi)
#pragma unroll
    for (int ni = 0; ni < 4; ++ni) {
      const int n = n0 + wc + ni * 16 + row16;
      const float bn = bias[n];
      if (MODE == 2) {
        const int mr0 = m0 + wr + mi * 16 + quad * 4;
        const int b = mr0 >> 10, l = mr0 & 1023;
        const int h = n >> 6, hd = n & 63;
        ushort4 o;
        o.x = f2bf(acc[mi][ni][0] + bn);
        o.y = f2bf(acc[mi][ni][1] + bn);
        o.z = f2bf(acc[mi][ni][2] + bn);
        o.w = f2bf(acc[mi][ni][3] + bn);
        *(ushort4*)&obf[((size_t)((b * HH + h) * HD + hd)) * LL + l] = o;
      } else {
#pragma unroll
        for (int r = 0; r < 4; ++r) {
          const int m = m0 + wr + mi * 16 + quad * 4 + r;
          const float v = acc[mi][ni][r] + bn;
          if (MODE == 0) {
            const int b = m >> 10, l = m & 1023, h = n >> 6, hd = n & 63;
            obf[((size_t)((b * HH + h) * LL + l)) * HD + hd] = f2bf(v);
          } else {
            ofp[(size_t)m * N + n] = v;
          }
        }
      }
    }
}

__global__ __launch_bounds__(256) void proj_gemm(
    const u16* __restrict__ xq, const u16* __restrict__ xk, const u16* __restrict__ xv,
    const u16* __restrict__ wqb, const u16* __restrict__ wkb, const u16* __restrict__ wvb,
    const float* __restrict__ bq, const float* __restrict__ bk, const float* __restrict__ bv,
    u16* __restrict__ oq, u16* __restrict__ ok, u16* __restrict__ ovt) {
  if (blockIdx.z == 0)
    gemm128_bt<0>(xq, wqb, bq, oq, nullptr, BB * LL, EE, EE, blockIdx.y * 128, blockIdx.x * 128);
  else if (blockIdx.z == 1)
    gemm128_bt<0>(xk, wkb, bk, ok, nullptr, BB * LL, EE, EE, blockIdx.y * 128, blockIdx.x * 128);
  else
    gemm128_bt<2>(xv, wvb, bv, ovt, nullptr, BB * LL, EE, EE, blockIdx.y * 128, blockIdx.x * 128);
}

__global__ __launch_bounds__(256) void out_gemm(const u16* __restrict__ Y,
                                                const u16* __restrict__ wob,
                                                const float* __restrict__ bo,
                                                float* __restrict__ out) {
  gemm128_bt<1>(Y, wob, bo, nullptr, out, BB * LL, EE, EE, blockIdx.y * 128, blockIdx.x * 128);
}

// ---------------- fused attention (round 4: swapped-operand, in-register P) -----
// Swap both MFMA operand orders: QK -> mfma(K,Q) so each lane holds S^T for ONE
// q-row (row16) and 16 j's; PV -> mfma(V,P) consuming a B-frag P assembled IN
// REGISTERS via 8 cvt_pk + 4 permlane32_swap. K tile loaded with row-perm rho'
// (rows 4-7 <-> 8-11 per 16) which makes the PV gather exactly {own, lane^32}:
//   (X,Y) = permlane32_swap(pk[2ks][rr], pk[2ks+1][rr]); frag = {X0,X1,Y0,Y1}.
// Eliminates per iter: 16 ds_write_b16 + 2 ds_read_b128 + mid barrier + lgkm
// drain (the LDS pipe was ~40% busy and barrier-aligned with the 38% VALU).
// LDS: kv 16384 (K 8K | V 8K) + qr 9216 + s 9216 = 34816 -> 4 blocks/CU.
__global__ __launch_bounds__(256) void attn_fused(
    const u16* __restrict__ Q, const u16* __restrict__ Kb, const u16* __restrict__ Vt,
    const u16* __restrict__ RKp, const float* __restrict__ RV, u16* __restrict__ Y) {
  __shared__ __align__(16) float qr_sm[4][576];     // [bucket][q] stride 17
  __shared__ __align__(16) float s_sm[4][16 * 36];  // [q][bucket] stride 36
  __shared__ __align__(16) unsigned char kv[16384]; // K 8K | V 8K; rv_sm epilogue

  const int tid = threadIdx.x;
  const int wave = tid >> 6, lane = tid & 63;
  const int row16 = lane & 15, quad = lane >> 4;
  const int bh = blockIdx.x & 63;          // XCD swizzle
  const int i0 = (blockIdx.x >> 6) * 64;
  const int wq0 = i0 + wave * 16;
  const u16* qp = Q + (size_t)bh * LL * HD;
  const char* kpB = (const char*)(Kb + (size_t)bh * LL * HD);
  const char* vpB = (const char*)(Vt + (size_t)bh * HD * LL);

  float* qr_w = &qr_sm[wave][0];
  float* s_w = &s_sm[wave][0];

  // stage offsets (both-sides swizzle: linear LDS dest, pre-swizzled source)
  int srcK[2], srcV[2];
#pragma unroll
  for (int t = 0; t < 2; ++t) {
    const int cK = (wave * 2 + t) * 64 + lane;
    const int rw = cK >> 3;
    const int cb = ((cK * 16) & 127) ^ ((rw & 7) << 4);
    srcK[t] = rw * 128 + cb;
    srcV[t] = rw * 2048 + cb;
  }
  // rho' row permutation (swap 4-7 <-> 8-11 within each 16) for K reads
  const int q2 = row16 >> 2;
  const int prow = ((((q2 << 1) | (q2 >> 1)) & 3) << 2) + (row16 & 3);
  const int swzK = (prow & 7) << 4;
  const int swzV = (row16 & 7) << 4;
  const int rho4 = (((quad << 1) | (quad >> 1)) & 3) << 2;  // rho(quad)*4

  // ---- prologue: issue stage of tile 0 first, overlap with qr compute ----
#pragma unroll
  for (int t = 0; t < 2; ++t) {
    gld_lds16(kpB + srcK[t], kv + (wave * 2 + t) * 1024);
    gld_lds16(vpB + srcV[t], kv + 8192 + (wave * 2 + t) * 1024);
  }

  for (int t = lane; t < 16 * 36; t += 64) s_w[t] = 0.f;

  // Q fragments (B-operand now; identical lane layout to A for 16x16x32)
  s16x8 qf[2];
#pragma unroll
  for (int ks = 0; ks < 2; ++ks)
    qf[ks] = *(const s16x8*)(qp + (size_t)(wq0 + row16) * HD + ks * 32 + quad * 8);

  // qr^T[bucket][q] = rel_k[bucket] . q  via swapped MFMA (A=RK, B=Q)
  f32x4 a0, a2;
#pragma unroll
  for (int nt = 0; nt < 3; ++nt) {
    f32x4 a = {};
#pragma unroll
    for (int ks = 0; ks < 2; ++ks) {
      s16x8 afr = *(const s16x8*)(RKp + (size_t)(nt * 16 + row16) * HD + ks * 32 + quad * 8);
      a = __builtin_amdgcn_mfma_f32_16x16x32_bf16(afr, qf[ks], a, 0, 0, 0);
    }
    if (nt == 0) a0 = a;
    if (nt == 2) a2 = a;
#pragma unroll
    for (int r = 0; r < 4; ++r) {
      const int bk = nt * 16 + quad * 4 + r;
      if (bk < NBUCKET) qr_w[bk * 17 + row16] = a[r];
    }
  }
  // far biases: bucket 0 / 32 value for this lane's q-row (= row16)
  const float blo = __shfl(a0[0], row16);
  const float bhi = __shfl(a2[0], row16);

  f32x4 oacc[4] = {};
  float rsum = 0.f, plos = 0.f, phis = 0.f;
  int baseg[4];
#pragma unroll
  for (int g = 0; g < 4; ++g) baseg[g] = g * 16 + rho4 - wq0 - row16;

  for (int jt = 0; jt < 16; ++jt) {
    const int j0 = jt * 64;
    if (jt) {  // re-stage K/V tile (single buffer; end-of-iter barrier fenced reads)
#pragma unroll
      for (int t = 0; t < 2; ++t) {
        gld_lds16(kpB + (size_t)j0 * 128 + srcK[t], kv + (wave * 2 + t) * 1024);
        gld_lds16(vpB + (size_t)j0 * 2 + srcV[t], kv + 8192 + (wave * 2 + t) * 1024);
      }
    }
    asm volatile("s_waitcnt vmcnt(0)" ::: "memory");
    __builtin_amdgcn_s_barrier();
    __builtin_amdgcn_sched_barrier(0);

    // ---- S^T = K Q^T : lane holds S^T[j = j0+g*16+rho4+r][q = wq0+row16] ----
    f32x4 sacc[4] = {};
#pragma unroll
    for (int ks = 0; ks < 2; ++ks)
#pragma unroll
      for (int g = 0; g < 4; ++g) {
        const int L = (g * 16 + prow) * 128 + ks * 64 + quad * 16;
        const s16x8 kfr = *(const s16x8*)(kv + (L ^ swzK));
        sacc[g] = __builtin_amdgcn_mfma_f32_16x16x32_bf16(kfr, qf[ks], sacc[g], 0, 0, 0);
      }

    // ---- softmax + bf16 pack (all in registers) ----
    unsigned pk[4][2];
    const bool far_lo = (wq0 >= j0 + 79);
    const bool far_hi = (j0 >= wq0 + 31);
    if (far_lo || far_hi) {
      const float bb = (far_lo ? blo : bhi) * SC2;
      float tacc = 0.f;
#pragma unroll
      for (int g = 0; g < 4; ++g)
#pragma unroll
        for (int rr = 0; rr < 2; ++rr) {
          const float pv0 = __builtin_amdgcn_exp2f(sacc[g][rr * 2] * SC2 + bb);
          const float pv1 = __builtin_amdgcn_exp2f(sacc[g][rr * 2 + 1] * SC2 + bb);
          tacc += pv0 + pv1;
          unsigned c;
          asm("v_cvt_pk_bf16_f32 %0, %1, %2" : "=v"(c) : "v"(pv0), "v"(pv1));
          pk[g][rr] = c;
        }
      rsum += tacc;
      if (far_lo) plos += tacc; else phis += tacc;
    } else {
#pragma unroll
      for (int g = 0; g < 4; ++g)
#pragma unroll
        for (int rr = 0; rr < 2; ++rr) {
          float pv2[2];
#pragma unroll
          for (int e = 0; e < 2; ++e) {
            const int r = rr * 2 + e;
            const int dr = baseg[g] + j0 + r;
            int bk = dr < -16 ? -16 : (dr > 16 ? 16 : dr);
            bk += 16;
            const float bias = qr_w[bk * 17 + row16];
            const float pv = __builtin_amdgcn_exp2f((sacc[g][r] + bias) * SC2);
            pv2[e] = pv;
            rsum += pv;
            if (dr <= -16) plos += pv;
            else if (dr >= 16) phis += pv;
            else atomicAdd(&s_w[row16 * 36 + bk], pv);
          }
          unsigned c;
          asm("v_cvt_pk_bf16_f32 %0, %1, %2" : "=v"(c) : "v"(pv2[0]), "v"(pv2[1]));
          pk[g][rr] = c;
        }
    }

    // ---- P^T B-frag assembly: 4 permlane32_swap, zero LDS ----
    s16x8 pf[2];
#pragma unroll
    for (int ks = 0; ks < 2; ++ks) {
      unsigned x0 = pk[ks * 2][0], y0 = pk[ks * 2 + 1][0];
      unsigned x1 = pk[ks * 2][1], y1 = pk[ks * 2 + 1][1];
      asm("v_permlane32_swap_b32 %0, %1" : "+v"(x0), "+v"(y0));
      asm("v_permlane32_swap_b32 %0, %1" : "+v"(x1), "+v"(y1));
      union { unsigned u[4]; s16x8 v; } pfu;
      pfu.u[0] = x0; pfu.u[1] = x1; pfu.u[2] = y0; pfu.u[3] = y1;
      pf[ks] = pfu.v;
    }

    // ---- O^T += V^T P^T ----
#pragma unroll
    for (int ks = 0; ks < 2; ++ks)
#pragma unroll
      for (int dt = 0; dt < 4; ++dt) {
        const int L = (dt * 16 + row16) * 128 + ks * 64 + quad * 16;
        const s16x8 vfr = *(const s16x8*)(kv + 8192 + (L ^ swzV));
        oacc[dt] = __builtin_amdgcn_mfma_f32_16x16x32_bf16(vfr, pf[ks], oacc[dt], 0, 0, 0);
      }

    asm volatile("s_waitcnt lgkmcnt(0)" ::: "memory");
    __builtin_amdgcn_s_barrier();
    __builtin_amdgcn_sched_barrier(0);
  }

  // quad-reduction of row sums (j space was split across quads)
  float t1 = rsum + __shfl_xor(rsum, 16);
  const float lacc = t1 + __shfl_xor(t1, 32);
  t1 = plos + __shfl_xor(plos, 16);
  const float slo = t1 + __shfl_xor(t1, 32);
  t1 = phis + __shfl_xor(phis, 16);
  const float shi = t1 + __shfl_xor(t1, 32);

  // epilogue: rel_v into kv (loop-final barrier fenced all reads)
  float* rv_sm = (float*)kv;
  for (int t = tid; t < NBUCKET * HD; t += 256) rv_sm[t] = RV[t];
  __syncthreads();

  const int b = bh >> 4, h = bh & 15;
  float rel[4][4] = {};
  for (int bk = 0; bk < NBUCKET; ++bk) {
    float sv = s_w[row16 * 36 + bk];
    if (bk == 0) sv += slo;
    if (bk == 32) sv += shi;
#pragma unroll
    for (int dt = 0; dt < 4; ++dt) {
      const f32x4 rv4 = *(const f32x4*)&rv_sm[bk * HD + dt * 16 + quad * 4];
#pragma unroll
      for (int r = 0; r < 4; ++r) rel[dt][r] += sv * rv4[r];
    }
  }
  const float inv = 1.0f / lacc;
#pragma unroll
  for (int dt = 0; dt < 4; ++dt) {
    ushort4 o;
    o.x = f2bf((oacc[dt][0] + rel[dt][0]) * inv);
    o.y = f2bf((oacc[dt][1] + rel[dt][1]) * inv);
    o.z = f2bf((oacc[dt][2] + rel[dt][2]) * inv);
    o.w = f2bf((oacc[dt][3] + rel[dt][3]) * inv);
    *(ushort4*)&Y[((size_t)(b * LL + wq0 + row16)) * EE + h * HD + dt * 16 + quad * 4] = o;
  }
}

extern "C" void kernel_launch(void* const* d_in, const int* in_sizes, int n_in,
                              void* d_out, int out_size, void* d_ws, size_t ws_size,
                              hipStream_t stream) {
  const float* query = (const float*)d_in[0];
  const float* key_  = (const float*)d_in[1];
  const float* value = (const float*)d_in[2];
  const float* wq = (const float*)d_in[3];
  const float* bq = (const float*)d_in[4];
  const float* wk = (const float*)d_in[5];
  const float* bk = (const float*)d_in[6];
  const float* wv = (const float*)d_in[7];
  const float* bv = (const float*)d_in[8];
  const float* wo = (const float*)d_in[9];
  const float* bo = (const float*)d_in[10];
  const float* rel_k = (const float*)d_in[11];
  const float* rel_v = (const float*)d_in[12];

  char* base = (char*)d_ws;
  size_t off = 0;
  auto alloc = [&](size_t bytes) -> void* {
    void* p = base + off;
    off += (bytes + 255) & ~(size_t)255;
    return p;
  };
  const size_t XE = (size_t)BB * LL * EE;
  u16* xq    = (u16*)alloc(XE * 2);
  u16* xk    = (u16*)alloc(XE * 2);
  u16* xv    = (u16*)alloc(XE * 2);
  u16* wqb   = (u16*)alloc((size_t)EE * EE * 2);
  u16* wkb   = (u16*)alloc((size_t)EE * EE * 2);
  u16* wvb   = (u16*)alloc((size_t)EE * EE * 2);
  u16* wob   = (u16*)alloc((size_t)EE * EE * 2);
  u16* q_ws  = (u16*)alloc(XE * 2);
  u16* k_ws  = (u16*)alloc(XE * 2);
  u16* vt_ws = (u16*)alloc(XE * 2);
  u16* relkp = (u16*)alloc(48 * 64 * 2);
  u16* y_ws = xq;   // xq dead after proj_gemm (stream-ordered)

  cvt_all<<<16396, 256, 0, stream>>>(query, key_, value, wq, wk, wv, wo, rel_k,
                                     xq, xk, xv, wqb, wkb, wvb, wob, relkp);

  proj_gemm<<<dim3(EE / 128, BB * LL / 128, 3), 256, 0, stream>>>(
      xq, xk, xv, wqb, wkb, wvb, bq, bk, bv, q_ws, k_ws, vt_ws);

  attn_fused<<<1024, 256, 0, stream>>>(q_ws, k_ws, vt_ws, relkp, rel_v, y_ws);

  out_gemm<<<dim3(EE / 128, BB * LL / 128), 256, 0, stream>>>(y_ws, wob, bo, (float*)d_out);
}